// Round 10
// baseline (487.576 us; speedup 1.0000x reference)
//
#include <hip/hip_runtime.h>

#define Dm  128
#define K1  64
#define TE3 256       // edges per block: 4 waves x 64 edges
#define LUT_ROWS 8    // LUT rows per prep block -> T/8 blocks (full-GPU parallel)

typedef _Float16 h8 __attribute__((ext_vector_type(8)));

__device__ __forceinline__ float ssp(float x) {
    return __logf(1.0f + __expf(x)) - 0.69314718056f;
}

__device__ __forceinline__ unsigned int pack_h2f(float a, float b) {
    _Float16 v[2] = {(_Float16)a, (_Float16)b};
    unsigned int u;
    __builtin_memcpy(&u, v, 4);
    return u;
}

// Fused prep, 256 threads/block:
//   [0, LUTB):        NN filter LUT (midpoint), 8 rows/block, 4 rows/thread
//   [LUTB, +ZB):      zero d_out
//   [LUTB+ZB, +CB):   convert atom_features f32 -> f16
__global__ void prep_all(const float* __restrict__ centers,
                         const float* __restrict__ gamma,
                         const float* __restrict__ W1,
                         const float* __restrict__ b1,
                         const float* __restrict__ W2,
                         const float* __restrict__ b2,
                         const float* __restrict__ af,
                         _Float16* __restrict__ tab,
                         _Float16* __restrict__ afh,
                         float* __restrict__ out,
                         int T, int LUTB, int ZB, int CB, int NATD) {
    __shared__ float rbf[LUT_ROWS][K1];    // 2 KB
    __shared__ float h1s[LUT_ROWS][Dm];    // 4 KB
    const int blk = blockIdx.x;
    const int t = threadIdx.x;             // 0..255

    if (blk < LUTB) {
        const int r0 = blk * LUT_ROWS;
        const float invT = 1.0f / (float)T;
        // 512 entries, 256 threads -> 2 strided iterations (R9 bug: single if)
        #pragma unroll
        for (int i = t; i < LUT_ROWS * K1; i += 256) {
            int r = i >> 6, k = i & 63;
            float d = ((float)(r0 + r) + 0.5f) * invT;   // midpoint sample
            float diff = d - centers[k];
            rbf[r][k] = __expf(-gamma[k] * diff * diff);
        }
        __syncthreads();
        const int ch = t & 127;
        const int rb = (t >> 7) * 4;       // rows [rb, rb+4)
        float acc[4];
        {
            float b = b1[ch];
            #pragma unroll
            for (int r = 0; r < 4; ++r) acc[r] = b;
        }
        #pragma unroll 4
        for (int k = 0; k < K1; ++k) {
            float w = W1[k * Dm + ch];
            #pragma unroll
            for (int r = 0; r < 4; ++r) acc[r] = fmaf(rbf[rb + r][k], w, acc[r]);
        }
        #pragma unroll
        for (int r = 0; r < 4; ++r) h1s[rb + r][ch] = ssp(acc[r]);
        __syncthreads();
        {
            float b = b2[ch];
            #pragma unroll
            for (int r = 0; r < 4; ++r) acc[r] = b;
        }
        #pragma unroll 4
        for (int k = 0; k < Dm; ++k) {
            float w = W2[k * Dm + ch];
            #pragma unroll
            for (int r = 0; r < 4; ++r) acc[r] = fmaf(h1s[rb + r][k], w, acc[r]);
        }
        #pragma unroll
        for (int r = 0; r < 4; ++r)
            tab[(size_t)(r0 + rb + r) * Dm + ch] = (_Float16)ssp(acc[r]);
    } else if (blk < LUTB + ZB) {
        const int b = blk - LUTB;
        float4* o4 = (float4*)out;
        const int n4 = NATD >> 2;
        const float4 z = make_float4(0.f, 0.f, 0.f, 0.f);
        for (int i = b * 256 + t; i < n4; i += ZB * 256) o4[i] = z;
    } else if (CB > 0) {
        const int b = blk - LUTB - ZB;
        const float4* a4 = (const float4*)af;
        uint2* d4 = (uint2*)afh;
        const int n4 = NATD >> 2;
        for (int i = b * 256 + t; i < n4; i += CB * 256) {
            float4 v = a4[i];
            uint2 st;
            st.x = pack_h2f(v.x, v.y);
            st.y = pack_h2f(v.z, v.w);
            d4[i] = st;
        }
    }
}

// Main: 16 lanes per edge, dwordx4 (8 f16) per lane. Each quarter-wave owns a
// contiguous 16-edge sorted range (run-compression intact); flushes are
// quarter-divergent exec-masked atomics.
template<bool AF16>
__global__ __launch_bounds__(256, 4) void cfconv_v5(
    const float* __restrict__ af,
    const _Float16* __restrict__ afh,
    const float* __restrict__ distances,
    const int*   __restrict__ idx_j,
    const int*   __restrict__ seg_i,
    const _Float16* __restrict__ tab,
    float* __restrict__ out, int T)
{
    __shared__ int4 meta[TE3];   // {idx_j, seg_i, lut row, pad}
    const int t = threadIdx.x;
    const long eb = (long)blockIdx.x * TE3;

    {
        float d = distances[eb + t];
        int iv = (int)(d * (float)T);
        iv = iv < 0 ? 0 : (iv > T - 1 ? T - 1 : iv);
        meta[t] = make_int4(idx_j[eb + t], seg_i[eb + t], iv, 0);
    }
    __syncthreads();

    const int lane = t & 63;
    const int g    = t >> 6;            // wave id: edges [g*64, g*64+64)
    const int eq   = lane >> 4;         // quarter: contiguous 16-edge subrange
    const int c8   = (lane & 15) * 8;   // 8-channel slot
    const int m0   = g * 64 + eq * 16;

    int cur = meta[m0].y;               // quarter-uniform (held per-lane)
    float s[8];
    #pragma unroll
    for (int i = 0; i < 8; ++i) s[i] = 0.f;

    #pragma unroll
    for (int b = 0; b < 2; ++b) {
        h8  tb[8], av[8];
        int sg[8];
        #pragma unroll
        for (int j = 0; j < 8; ++j) {
            int4 md = meta[m0 + b * 8 + j];
            sg[j] = md.y;
            tb[j] = *(const h8*)&tab[(size_t)md.z * Dm + c8];
            if (AF16) {
                av[j] = *(const h8*)&afh[(size_t)md.x * Dm + c8];
            } else {
                float4 a0 = *(const float4*)&af[(size_t)md.x * Dm + c8];
                float4 a1 = *(const float4*)&af[(size_t)md.x * Dm + c8 + 4];
                av[j][0] = (_Float16)a0.x; av[j][1] = (_Float16)a0.y;
                av[j][2] = (_Float16)a0.z; av[j][3] = (_Float16)a0.w;
                av[j][4] = (_Float16)a1.x; av[j][5] = (_Float16)a1.y;
                av[j][6] = (_Float16)a1.z; av[j][7] = (_Float16)a1.w;
            }
        }
        #pragma unroll
        for (int j = 0; j < 8; ++j) {
            if (sg[j] != cur) {          // quarter-divergent, rare (~2/16)
                float* op = &out[(size_t)cur * Dm + c8];
                #pragma unroll
                for (int i = 0; i < 8; ++i) atomicAdd(op + i, s[i]);
                #pragma unroll
                for (int i = 0; i < 8; ++i) s[i] = 0.f;
                cur = sg[j];
            }
            #pragma unroll
            for (int i = 0; i < 8; ++i)   // v_fma_mix_f32: f16*f16 + f32
                s[i] = fmaf((float)tb[j][i], (float)av[j][i], s[i]);
        }
    }
    float* op = &out[(size_t)cur * Dm + c8];
    #pragma unroll
    for (int i = 0; i < 8; ++i) atomicAdd(op + i, s[i]);
}

extern "C" void kernel_launch(void* const* d_in, const int* in_sizes, int n_in,
                              void* d_out, int out_size, void* d_ws, size_t ws_size,
                              hipStream_t stream) {
    const float* atom_features = (const float*)d_in[0];
    const float* distances     = (const float*)d_in[1];
    const int*   idx_j         = (const int*)d_in[2];
    const int*   seg_i         = (const int*)d_in[3];
    const float* centers       = (const float*)d_in[4];
    const float* gamma         = (const float*)d_in[5];
    const float* W1            = (const float*)d_in[6];
    const float* b1            = (const float*)d_in[7];
    const float* W2            = (const float*)d_in[8];
    const float* b2            = (const float*)d_in[9];

    const int E    = in_sizes[1];   // 800000, divisible by TE3=256
    const int NATD = out_size;      // 50000*128
    float* out = (float*)d_out;

    // ws: [tab: T*Dm*2 bytes][afh: NATD*2 bytes]
    int T; bool af16;
    const size_t afh_bytes = (size_t)NATD * 2;
    if      (ws_size >= (size_t)2048 * Dm * 2 + afh_bytes) { T = 2048; af16 = true;  }
    else if (ws_size >= (size_t)2048 * Dm * 2)             { T = 2048; af16 = false; }
    else                                                   { T = 512;  af16 = false; }

    _Float16* tab = (_Float16*)d_ws;
    _Float16* afh = (_Float16*)((char*)d_ws + (size_t)T * Dm * 2);

    const int LUTB = T / LUT_ROWS;      // 256 blocks at T=2048
    const int ZB = 256;
    const int CB = af16 ? 256 : 0;
    prep_all<<<LUTB + ZB + CB, 256, 0, stream>>>(
        centers, gamma, W1, b1, W2, b2, atom_features,
        tab, afh, out, T, LUTB, ZB, CB, NATD);

    if (af16)
        cfconv_v5<true><<<E / TE3, 256, 0, stream>>>(
            atom_features, afh, distances, idx_j, seg_i, tab, out, T);
    else
        cfconv_v5<false><<<E / TE3, 256, 0, stream>>>(
            atom_features, afh, distances, idx_j, seg_i, tab, out, T);
}

// Round 11
// 157.079 us; speedup vs baseline: 3.1040x; 3.1040x over previous
//
#include <hip/hip_runtime.h>

#define Dm  128
#define K1  64
#define TE3 256       // edges per block: 4 waves x 4 quarters x 16 edges
#define LUT_ROWS 8    // LUT rows per prep block -> T/8 blocks (full-GPU parallel)

typedef _Float16 h8 __attribute__((ext_vector_type(8)));

__device__ __forceinline__ float ssp(float x) {
    return __logf(1.0f + __expf(x)) - 0.69314718056f;
}

__device__ __forceinline__ unsigned int pack_h2f(float a, float b) {
    _Float16 v[2] = {(_Float16)a, (_Float16)b};
    unsigned int u;
    __builtin_memcpy(&u, v, 4);
    return u;
}

// Fused prep, 256 threads/block:
//   [0, LUTB):        NN filter LUT (midpoint), 8 rows/block, 4 rows/thread
//   [LUTB, +ZB):      zero d_out
//   [LUTB+ZB, +CB):   convert atom_features f32 -> f16
__global__ void prep_all(const float* __restrict__ centers,
                         const float* __restrict__ gamma,
                         const float* __restrict__ W1,
                         const float* __restrict__ b1,
                         const float* __restrict__ W2,
                         const float* __restrict__ b2,
                         const float* __restrict__ af,
                         _Float16* __restrict__ tab,
                         _Float16* __restrict__ afh,
                         float* __restrict__ out,
                         int T, int LUTB, int ZB, int CB, int NATD) {
    __shared__ float rbf[LUT_ROWS][K1];    // 2 KB
    __shared__ float h1s[LUT_ROWS][Dm];    // 4 KB
    const int blk = blockIdx.x;
    const int t = threadIdx.x;             // 0..255

    if (blk < LUTB) {
        const int r0 = blk * LUT_ROWS;
        const float invT = 1.0f / (float)T;
        // 512 entries, 256 threads -> 2 strided iterations
        #pragma unroll
        for (int i = t; i < LUT_ROWS * K1; i += 256) {
            int r = i >> 6, k = i & 63;
            float d = ((float)(r0 + r) + 0.5f) * invT;   // midpoint sample
            float diff = d - centers[k];
            rbf[r][k] = __expf(-gamma[k] * diff * diff);
        }
        __syncthreads();
        const int ch = t & 127;
        const int rb = (t >> 7) * 4;       // rows [rb, rb+4)
        float acc[4];
        {
            float b = b1[ch];
            #pragma unroll
            for (int r = 0; r < 4; ++r) acc[r] = b;
        }
        #pragma unroll 4
        for (int k = 0; k < K1; ++k) {
            float w = W1[k * Dm + ch];
            #pragma unroll
            for (int r = 0; r < 4; ++r) acc[r] = fmaf(rbf[rb + r][k], w, acc[r]);
        }
        #pragma unroll
        for (int r = 0; r < 4; ++r) h1s[rb + r][ch] = ssp(acc[r]);
        __syncthreads();
        {
            float b = b2[ch];
            #pragma unroll
            for (int r = 0; r < 4; ++r) acc[r] = b;
        }
        #pragma unroll 4
        for (int k = 0; k < Dm; ++k) {
            float w = W2[k * Dm + ch];
            #pragma unroll
            for (int r = 0; r < 4; ++r) acc[r] = fmaf(h1s[rb + r][k], w, acc[r]);
        }
        #pragma unroll
        for (int r = 0; r < 4; ++r)
            tab[(size_t)(r0 + rb + r) * Dm + ch] = (_Float16)ssp(acc[r]);
    } else if (blk < LUTB + ZB) {
        const int b = blk - LUTB;
        float4* o4 = (float4*)out;
        const int n4 = NATD >> 2;
        const float4 z = make_float4(0.f, 0.f, 0.f, 0.f);
        for (int i = b * 256 + t; i < n4; i += ZB * 256) o4[i] = z;
    } else if (CB > 0) {
        const int b = blk - LUTB - ZB;
        const float4* a4 = (const float4*)af;
        uint2* d4 = (uint2*)afh;
        const int n4 = NATD >> 2;
        for (int i = b * 256 + t; i < n4; i += CB * 256) {
            float4 v = a4[i];
            uint2 st;
            st.x = pack_h2f(v.x, v.y);
            st.y = pack_h2f(v.z, v.w);
            d4[i] = st;
        }
    }
}

// Main: 16 lanes per edge, dwordx4 (8 f16) per lane. Each quarter-wave owns a
// contiguous 16-edge sorted range. Flushes transpose through LDS so every
// atomic instruction writes one full contiguous 64B line (R10 regression:
// strided lanes -> 64 partial-line RMW touches per flush -> write-path wall).
template<bool AF16>
__global__ __launch_bounds__(256, 4) void cfconv_v6(
    const float* __restrict__ af,
    const _Float16* __restrict__ afh,
    const float* __restrict__ distances,
    const int*   __restrict__ idx_j,
    const int*   __restrict__ seg_i,
    const _Float16* __restrict__ tab,
    float* __restrict__ out, int T)
{
    __shared__ int4  meta[TE3];        // {idx_j, seg_i, lut row, pad}  4 KB
    __shared__ float xscr[16 * 128];   // per-quarter transpose scratch 8 KB
    const int t = threadIdx.x;
    const long eb = (long)blockIdx.x * TE3;

    {
        float d = distances[eb + t];
        int iv = (int)(d * (float)T);
        iv = iv < 0 ? 0 : (iv > T - 1 ? T - 1 : iv);
        meta[t] = make_int4(idx_j[eb + t], seg_i[eb + t], iv, 0);
    }
    __syncthreads();

    const int lane = t & 63;
    const int g    = t >> 6;            // wave id
    const int eq   = lane >> 4;         // quarter: contiguous 16-edge subrange
    const int li   = lane & 15;
    const int c8   = li * 8;            // 8-channel slot owned during gather
    const int m0   = g * 64 + eq * 16;
    float* xp = &xscr[(t >> 4) * 128];  // this quarter's 512B scratch

    int cur = meta[m0].y;               // quarter-uniform (held per-lane)
    float s[8];
    #pragma unroll
    for (int i = 0; i < 8; ++i) s[i] = 0.f;

    // quarter-lockstep flush: stage 16x8 block in LDS, read transposed so
    // atomic instr j covers out[cur*128 + j*16 + (0..15)] = one 64B line.
    auto flush = [&](int seg) {
        *(float4*)&xp[c8]     = make_float4(s[0], s[1], s[2], s[3]);
        *(float4*)&xp[c8 + 4] = make_float4(s[4], s[5], s[6], s[7]);
        float* op = &out[(size_t)seg * Dm];
        #pragma unroll
        for (int j = 0; j < 8; ++j)
            atomicAdd(op + j * 16 + li, xp[j * 16 + li]);
    };

    #pragma unroll
    for (int b = 0; b < 2; ++b) {
        h8  tb[8], av[8];
        int sg[8];
        #pragma unroll
        for (int j = 0; j < 8; ++j) {
            int4 md = meta[m0 + b * 8 + j];
            sg[j] = md.y;
            tb[j] = *(const h8*)&tab[(size_t)md.z * Dm + c8];
            if (AF16) {
                av[j] = *(const h8*)&afh[(size_t)md.x * Dm + c8];
            } else {
                float4 a0 = *(const float4*)&af[(size_t)md.x * Dm + c8];
                float4 a1 = *(const float4*)&af[(size_t)md.x * Dm + c8 + 4];
                av[j][0] = (_Float16)a0.x; av[j][1] = (_Float16)a0.y;
                av[j][2] = (_Float16)a0.z; av[j][3] = (_Float16)a0.w;
                av[j][4] = (_Float16)a1.x; av[j][5] = (_Float16)a1.y;
                av[j][6] = (_Float16)a1.z; av[j][7] = (_Float16)a1.w;
            }
        }
        #pragma unroll
        for (int j = 0; j < 8; ++j) {
            if (sg[j] != cur) {          // quarter-divergent, rare (~2/16)
                flush(cur);
                #pragma unroll
                for (int i = 0; i < 8; ++i) s[i] = 0.f;
                cur = sg[j];
            }
            #pragma unroll
            for (int i = 0; i < 8; ++i)   // v_fma_mix_f32: f16*f16 + f32
                s[i] = fmaf((float)tb[j][i], (float)av[j][i], s[i]);
        }
    }
    flush(cur);
}

extern "C" void kernel_launch(void* const* d_in, const int* in_sizes, int n_in,
                              void* d_out, int out_size, void* d_ws, size_t ws_size,
                              hipStream_t stream) {
    const float* atom_features = (const float*)d_in[0];
    const float* distances     = (const float*)d_in[1];
    const int*   idx_j         = (const int*)d_in[2];
    const int*   seg_i         = (const int*)d_in[3];
    const float* centers       = (const float*)d_in[4];
    const float* gamma         = (const float*)d_in[5];
    const float* W1            = (const float*)d_in[6];
    const float* b1            = (const float*)d_in[7];
    const float* W2            = (const float*)d_in[8];
    const float* b2            = (const float*)d_in[9];

    const int E    = in_sizes[1];   // 800000, divisible by TE3=256
    const int NATD = out_size;      // 50000*128
    float* out = (float*)d_out;

    // ws: [tab: T*Dm*2 bytes][afh: NATD*2 bytes]
    int T; bool af16;
    const size_t afh_bytes = (size_t)NATD * 2;
    if      (ws_size >= (size_t)2048 * Dm * 2 + afh_bytes) { T = 2048; af16 = true;  }
    else if (ws_size >= (size_t)2048 * Dm * 2)             { T = 2048; af16 = false; }
    else                                                   { T = 512;  af16 = false; }

    _Float16* tab = (_Float16*)d_ws;
    _Float16* afh = (_Float16*)((char*)d_ws + (size_t)T * Dm * 2);

    const int LUTB = T / LUT_ROWS;      // 256 blocks at T=2048
    const int ZB = 256;
    const int CB = af16 ? 256 : 0;
    prep_all<<<LUTB + ZB + CB, 256, 0, stream>>>(
        centers, gamma, W1, b1, W2, b2, atom_features,
        tab, afh, out, T, LUTB, ZB, CB, NATD);

    if (af16)
        cfconv_v6<true><<<E / TE3, 256, 0, stream>>>(
            atom_features, afh, distances, idx_j, seg_i, tab, out, T);
    else
        cfconv_v6<false><<<E / TE3, 256, 0, stream>>>(
            atom_features, afh, distances, idx_j, seg_i, tab, out, T);
}